// Round 5
// baseline (230.393 us; speedup 1.0000x reference)
//
#include <hip/hip_runtime.h>
#include <hip/hip_bf16.h>

// MetaConv2d fused hypernetwork + dynamic conv, bf16 MFMA. Round 5.
// out[bn,t,o] = sum_{c,k} x[bn,t+k,c] * w[bn,o,c,k] + bias[bn,o]
//   w[bn,p]   = meta[bn,:]·w_lin_w[p,:] + w_lin_b[p],  p = o*192 + c*3 + k
//
// Block = 8 nodes, 1024 threads (16 waves = 8 nodes x 2 t-halves), grid 1024.
// NEW vs r3: x slab staged once into LDS as bf16 with a deep load queue
// (8 independent float4 loads/lane) -> HBM becomes BW-bound, not latency-bound.
// Phases (4 = 2 c-chunks x 2 o-halves) then touch only LDS + L2-resident wlwbf:
//   { hyper (12 tiles/wave, 2 groups of 6) -> w_lds; barrier;
//     conv (6 B + 6 A ds_reads, 12 MFMA into persistent acc); barrier; }
// LDS: dynamic 119 KB = x 64 KB + w 53.4 KB; static 2 KB bias.

#define BN_TOT   8192
#define C_IN     64
#define C_OUT    64
#define M_DIM    32
#define S_OUT    62

#define NT       8            // nodes per block
#define NTHREADS 1024         // 16 waves
#define OSTR     104          // shorts per o-row in w_lds: 96 j + 8 pad
#define NODESTR  3336         // 32*OSTR + 8 (bank-spread across nodes)
#define WLDSN    (NT * NODESTR)      // 26688 shorts
#define XLDSN    (NT * 64 * 64)      // 32768 shorts (x bf16, [node][t][c])
#define DYNB     ((XLDSN + WLDSN) * 2)   // 118912 B
#define WLW_ROWS 12288
#define WS_NEED  (WLW_ROWS * M_DIM * 2 + WLW_ROWS * 4)

typedef __attribute__((ext_vector_type(8))) short bf16x8;
typedef __attribute__((ext_vector_type(4))) float f32x4;

static __device__ __forceinline__ short f2bf(float f) {
    return __bfloat16_as_short(__float2bfloat16(f));
}

static __device__ __forceinline__ bf16x8 cvt8(float4 a, float4 b) {
    bf16x8 r;
    r[0] = f2bf(a.x); r[1] = f2bf(a.y); r[2] = f2bf(a.z); r[3] = f2bf(a.w);
    r[4] = f2bf(b.x); r[5] = f2bf(b.y); r[6] = f2bf(b.z); r[7] = f2bf(b.w);
    return r;
}

// ---------------- pre-pass 1: w_lin_w f32 -> bf16 ----------------
extern "C" __global__ void wlw_to_bf16(const float* __restrict__ src,
                                       short* __restrict__ dst) {
    const int i = (blockIdx.x * 256 + threadIdx.x) * 8;
    const float4 a = *reinterpret_cast<const float4*>(src + i);
    const float4 b = *reinterpret_cast<const float4*>(src + i + 4);
    *reinterpret_cast<bf16x8*>(dst + i) = cvt8(a, b);
}

// ---------------- pre-pass 2: wlb -> wlbR[o][k][c] f32 ----------------
extern "C" __global__ void wlb_rearr(const float* __restrict__ wlb,
                                     float* __restrict__ wlbR) {
    const int i = blockIdx.x * 256 + threadIdx.x;
    const int o = i / 192;
    const int r = i - o * 192;
    const int k = r >> 6;
    const int c = r & 63;
    wlbR[i] = wlb[o * 192 + c * 3 + k];
}

// ---------------- fused kernel ----------------
template <int USE_WS>
__global__ void __launch_bounds__(NTHREADS, 4)
metaconv_fused(const float* __restrict__ meta,   // [8192][32]
               const float* __restrict__ x,      // [8192][64][64]
               const float* __restrict__ wlw,    // [12288][32] f32
               const short* __restrict__ wlwbf,  // [12288][32] bf16 (ws)
               const float* __restrict__ wlb,    // [12288]
               const float* __restrict__ wlbR,   // [64][3][64] (ws)
               const float* __restrict__ blw,    // [64][32]
               const float* __restrict__ blb,    // [64]
               float* __restrict__ out)          // [8192][62][64]
{
    extern __shared__ __align__(16) short dynsm[];
    short* xsh = dynsm;                  // [8][64][64] bf16
    short* wsh = dynsm + XLDSN;          // [8][NODESTR]
    __shared__ float bias_s[NT][C_OUT];

    const int tid   = threadIdx.x;
    const int wave  = tid >> 6;          // 0..15
    const int lane  = tid & 63;
    const int l16   = lane & 15;
    const int g     = lane >> 4;
    const int node  = wave & (NT - 1);
    const int thalf = wave >> 3;
    const int bn0   = blockIdx.x * NT;

    // ---- stage x slab: 8 independent float4 loads/lane (deep HBM queue) ----
    {
        const float* xsrc = x + (size_t)(bn0 + node) * (64 * C_IN);
        short* xdst = xsh + node * 4096;
        const int ts0 = thalf * 32;
        #pragma unroll
        for (int i = 0; i < 4; ++i) {
            const int gi = i * 64 + lane;          // 0..255 granules (32 t x 8)
            const int tl = ts0 + (gi >> 3);
            const int gr = gi & 7;
            const float4 a = *reinterpret_cast<const float4*>(xsrc + tl * 64 + gr * 8);
            const float4 b = *reinterpret_cast<const float4*>(xsrc + tl * 64 + gr * 8 + 4);
            *reinterpret_cast<bf16x8*>(xdst + tl * 64 + gr * 8) = cvt8(a, b);
        }
    }

    // per-block bias table (tid < 512)
    if (tid < NT * C_OUT) {
        const int bnode = tid >> 6;
        const int o     = tid & 63;
        const float* mrow = meta + (size_t)(bn0 + bnode) * M_DIM;
        const float* brow = blw + o * M_DIM;
        float s = blb[o];
        #pragma unroll
        for (int m = 0; m < M_DIM; ++m) s += mrow[m] * brow[m];
        bias_s[bnode][o] = s;
    }

    // meta B-fragment (cols = nodes; cols 8..15 duplicate, discarded on write)
    bf16x8 metaF;
    {
        const float* mp = meta + (size_t)(bn0 + (l16 & (NT - 1))) * M_DIM + g * 8;
        metaF = cvt8(*reinterpret_cast<const float4*>(mp),
                     *reinterpret_cast<const float4*>(mp + 4));
    }

    const f32x4 ZV = {0.f, 0.f, 0.f, 0.f};
    f32x4 acc[2][4];                     // [t-tile local][o-tile 0..3]
    #pragma unroll
    for (int t = 0; t < 2; ++t)
        #pragma unroll
        for (int o = 0; o < 4; ++o) acc[t][o] = ZV;

    __syncthreads();                     // x staged, bias ready

    #pragma unroll 1
    for (int p = 0; p < 4; ++p) {
        const int c0 = (p >> 1) * 32;
        const int oh = p & 1;

        // ---- hyper: 12 tiles/wave = 2 groups of 6 (r3's proven flight depth)
        #pragma unroll 1
        for (int ou = 0; ou < 2; ++ou) {
            const int o_l = wave * 2 + ou;       // 0..31 within half
            const int og  = oh * 32 + o_l;       // global o
            #pragma unroll
            for (int ch = 0; ch < 2; ++ch) {
                #pragma unroll
                for (int k = 0; k < 3; ++k) {
                    const int pr = og * 192 + (c0 + ch * 16 + l16) * 3 + k;
                    bf16x8 aF;
                    f32x4 Cf;
                    if constexpr (USE_WS) {
                        aF = *reinterpret_cast<const bf16x8*>(wlwbf + (size_t)pr * M_DIM + g * 8);
                        const float4 cf = *reinterpret_cast<const float4*>(
                            wlbR + (og * 3 + k) * 64 + c0 + ch * 16 + g * 4);
                        Cf[0] = cf.x; Cf[1] = cf.y; Cf[2] = cf.z; Cf[3] = cf.w;
                    } else {
                        const float* wp = wlw + (size_t)pr * M_DIM + g * 8;
                        aF = cvt8(*reinterpret_cast<const float4*>(wp),
                                  *reinterpret_cast<const float4*>(wp + 4));
                        const int cb = c0 + ch * 16 + g * 4;
                        const int pb = og * 192 + k;
                        Cf[0] = wlb[pb + (cb + 0) * 3];
                        Cf[1] = wlb[pb + (cb + 1) * 3];
                        Cf[2] = wlb[pb + (cb + 2) * 3];
                        Cf[3] = wlb[pb + (cb + 3) * 3];
                    }
                    const f32x4 d = __builtin_amdgcn_mfma_f32_16x16x32_bf16(aF, metaF, Cf, 0, 0, 0);
                    if (l16 < NT) {
                        const int off = l16 * NODESTR + o_l * OSTR + k * 32 + ch * 16 + g * 4;
                        *reinterpret_cast<short4*>(&wsh[off]) =
                            make_short4(f2bf(d[0]), f2bf(d[1]), f2bf(d[2]), f2bf(d[3]));
                    }
                }
            }
        }
        __syncthreads();                 // w ready for conv

        // ---- conv: B-frags (LDS), A-frags (LDS), 12 MFMA ----
        const short* wn = wsh + node * NODESTR;
        const short* xn = xsh + node * 4096;
        bf16x8 B[2][3];
        #pragma unroll
        for (int ol = 0; ol < 2; ++ol)
            #pragma unroll
            for (int k = 0; k < 3; ++k)
                B[ol][k] = *reinterpret_cast<const bf16x8*>(
                    wn + (ol * 16 + l16) * OSTR + k * 32 + g * 8);

        #pragma unroll
        for (int ttl = 0; ttl < 2; ++ttl) {
            #pragma unroll
            for (int k = 0; k < 3; ++k) {
                int row = thalf * 32 + ttl * 16 + l16 + k;
                row = row < 63 ? row : 63;         // rows t>=62 discarded
                const bf16x8 A = *reinterpret_cast<const bf16x8*>(
                    xn + row * 64 + c0 + g * 8);
                #pragma unroll
                for (int ol = 0; ol < 2; ++ol)
                    acc[ttl][oh * 2 + ol] = __builtin_amdgcn_mfma_f32_16x16x32_bf16(
                        A, B[ol][k], acc[ttl][oh * 2 + ol], 0, 0, 0);
            }
        }
        __syncthreads();                 // conv done before next hyper overwrite
    }

    // ---------------- epilogue: add bias, store f32 ----------------
    float* ob = out + (size_t)(bn0 + node) * (S_OUT * C_OUT);
    #pragma unroll
    for (int ttl = 0; ttl < 2; ++ttl) {
        #pragma unroll
        for (int ot = 0; ot < 4; ++ot) {
            const int o  = ot * 16 + l16;
            const float bv = bias_s[node][o];
            #pragma unroll
            for (int r = 0; r < 4; ++r) {
                const int t = thalf * 32 + ttl * 16 + g * 4 + r;
                if (t < S_OUT) ob[t * C_OUT + o] = acc[ttl][ot][r] + bv;
            }
        }
    }
}

extern "C" void kernel_launch(void* const* d_in, const int* in_sizes, int n_in,
                              void* d_out, int out_size, void* d_ws, size_t ws_size,
                              hipStream_t stream) {
    const float* meta = (const float*)d_in[0];
    const float* x    = (const float*)d_in[1];
    const float* wlw  = (const float*)d_in[2];
    const float* wlb  = (const float*)d_in[3];
    const float* blw  = (const float*)d_in[4];
    const float* blb  = (const float*)d_in[5];
    float* out = (float*)d_out;
    (void)in_sizes; (void)n_in; (void)out_size;

    short* wlwbf = (short*)d_ws;
    float* wlbR  = (float*)((char*)d_ws + (size_t)WLW_ROWS * M_DIM * 2);

    if (ws_size >= (size_t)WS_NEED) {
        (void)hipFuncSetAttribute((const void*)&metaconv_fused<1>,
                                  hipFuncAttributeMaxDynamicSharedMemorySize, DYNB);
        wlw_to_bf16<<<dim3(WLW_ROWS * M_DIM / (256 * 8)), dim3(256), 0, stream>>>(wlw, wlwbf);
        wlb_rearr<<<dim3(WLW_ROWS / 256), dim3(256), 0, stream>>>(wlb, wlbR);
        metaconv_fused<1><<<dim3(BN_TOT / NT), dim3(NTHREADS), DYNB, stream>>>(
            meta, x, wlw, wlwbf, wlb, wlbR, blw, blb, out);
    } else {
        (void)hipFuncSetAttribute((const void*)&metaconv_fused<0>,
                                  hipFuncAttributeMaxDynamicSharedMemorySize, DYNB);
        metaconv_fused<0><<<dim3(BN_TOT / NT), dim3(NTHREADS), DYNB, stream>>>(
            meta, x, wlw, wlwbf, wlb, wlbR, blw, blb, out);
    }
}

// Round 6
// 143.159 us; speedup vs baseline: 1.6094x; 1.6094x over previous
//
#include <hip/hip_runtime.h>
#include <hip/hip_bf16.h>

// MetaConv2d fused hypernetwork + dynamic conv, bf16 MFMA. Round 6.
// out[bn,t,o] = sum_{c,k} x[bn,t+k,c] * w[bn,o,c,k] + bias[bn,o]
//   w[bn,p]   = meta[bn,:]·w_lin_w[p,:] + w_lin_b[p],  p = o*192 + c*3 + k
//
// Block = 8 nodes, 1024 threads (16 waves = 8 nodes x 2 t-halves), grid 1024.
// r5's x-LDS staging (deep HBM queue at block start) with two fixes:
//  - acc indices are ALL compile-time (runtime-indexed acc in r5 went to scratch:
//    VGPR 64->36, WRITE 127->520 MB). Loop shape: unroll1(cchunk) x unroll(oh).
//  - xsh XOR-swizzled (idx ^= (row&7)<<3, write AND read) -> A-reads 2-way banks.
// Phases (4 = 2 c-chunks x 2 o-halves):
//   { hyper (12 tiles/wave, 2 groups of 6) -> w_lds; barrier;
//     conv (6 B + 6 A ds_reads, 12 MFMA into persistent acc); barrier; }
// LDS: dynamic 119 KB = x 64 KB + w 53.4 KB; static 2 KB bias.

#define BN_TOT   8192
#define C_IN     64
#define C_OUT    64
#define M_DIM    32
#define S_OUT    62

#define NT       8            // nodes per block
#define NTHREADS 1024         // 16 waves
#define OSTR     104          // shorts per o-row in w_lds: 96 j + 8 pad (13 dwords: odd -> conflict-free)
#define NODESTR  3336         // 32*OSTR + 8
#define WLDSN    (NT * NODESTR)      // 26688 shorts
#define XLDSN    (NT * 64 * 64)      // 32768 shorts (x bf16, [node][t][c] swizzled)
#define DYNB     ((XLDSN + WLDSN) * 2)   // 118912 B
#define WLW_ROWS 12288
#define WS_NEED  (WLW_ROWS * M_DIM * 2 + WLW_ROWS * 4)

typedef __attribute__((ext_vector_type(8))) short bf16x8;
typedef __attribute__((ext_vector_type(4))) float f32x4;

static __device__ __forceinline__ short f2bf(float f) {
    return __bfloat16_as_short(__float2bfloat16(f));
}

static __device__ __forceinline__ bf16x8 cvt8(float4 a, float4 b) {
    bf16x8 r;
    r[0] = f2bf(a.x); r[1] = f2bf(a.y); r[2] = f2bf(a.z); r[3] = f2bf(a.w);
    r[4] = f2bf(b.x); r[5] = f2bf(b.y); r[6] = f2bf(b.z); r[7] = f2bf(b.w);
    return r;
}

// ---------------- pre-pass 1: w_lin_w f32 -> bf16 ----------------
extern "C" __global__ void wlw_to_bf16(const float* __restrict__ src,
                                       short* __restrict__ dst) {
    const int i = (blockIdx.x * 256 + threadIdx.x) * 8;
    const float4 a = *reinterpret_cast<const float4*>(src + i);
    const float4 b = *reinterpret_cast<const float4*>(src + i + 4);
    *reinterpret_cast<bf16x8*>(dst + i) = cvt8(a, b);
}

// ---------------- pre-pass 2: wlb -> wlbR[o][k][c] f32 ----------------
extern "C" __global__ void wlb_rearr(const float* __restrict__ wlb,
                                     float* __restrict__ wlbR) {
    const int i = blockIdx.x * 256 + threadIdx.x;
    const int o = i / 192;
    const int r = i - o * 192;
    const int k = r >> 6;
    const int c = r & 63;
    wlbR[i] = wlb[o * 192 + c * 3 + k];
}

// ---------------- fused kernel ----------------
template <int USE_WS>
__global__ void __launch_bounds__(NTHREADS, 4)
metaconv_fused(const float* __restrict__ meta,   // [8192][32]
               const float* __restrict__ x,      // [8192][64][64]
               const float* __restrict__ wlw,    // [12288][32] f32
               const short* __restrict__ wlwbf,  // [12288][32] bf16 (ws)
               const float* __restrict__ wlb,    // [12288]
               const float* __restrict__ wlbR,   // [64][3][64] (ws)
               const float* __restrict__ blw,    // [64][32]
               const float* __restrict__ blb,    // [64]
               float* __restrict__ out)          // [8192][62][64]
{
    extern __shared__ __align__(16) short dynsm[];
    short* xsh = dynsm;                  // [8][64][64] bf16, row-swizzled
    short* wsh = dynsm + XLDSN;          // [8][NODESTR]
    __shared__ float bias_s[NT][C_OUT];

    const int tid   = threadIdx.x;
    const int wave  = tid >> 6;          // 0..15
    const int lane  = tid & 63;
    const int l16   = lane & 15;
    const int g     = lane >> 4;
    const int node  = wave & (NT - 1);
    const int thalf = wave >> 3;
    const int bn0   = blockIdx.x * NT;

    // ---- stage x slab: 8 independent float4 loads/lane (deep HBM queue) ----
    // xsh layout: node*4096 + t*64 + (granule*8 ^ ((t&7)<<3))   [shorts]
    {
        const float* xsrc = x + (size_t)(bn0 + node) * (64 * C_IN);
        short* xdst = xsh + node * 4096;
        const int ts0 = thalf * 32;
        #pragma unroll
        for (int i = 0; i < 4; ++i) {
            const int gi = i * 64 + lane;          // 0..255 granules (32 t x 8)
            const int tl = ts0 + (gi >> 3);
            const int gr = gi & 7;
            const float4 a = *reinterpret_cast<const float4*>(xsrc + tl * 64 + gr * 8);
            const float4 b = *reinterpret_cast<const float4*>(xsrc + tl * 64 + gr * 8 + 4);
            const int so = (gr * 8) ^ ((tl & 7) << 3);
            *reinterpret_cast<bf16x8*>(xdst + tl * 64 + so) = cvt8(a, b);
        }
    }

    // per-block bias table (tid < 512)
    if (tid < NT * C_OUT) {
        const int bnode = tid >> 6;
        const int o     = tid & 63;
        const float* mrow = meta + (size_t)(bn0 + bnode) * M_DIM;
        const float* brow = blw + o * M_DIM;
        float s = blb[o];
        #pragma unroll
        for (int m = 0; m < M_DIM; ++m) s += mrow[m] * brow[m];
        bias_s[bnode][o] = s;
    }

    // meta B-fragment (cols = nodes; cols 8..15 duplicate, discarded on write)
    bf16x8 metaF;
    {
        const float* mp = meta + (size_t)(bn0 + (l16 & (NT - 1))) * M_DIM + g * 8;
        metaF = cvt8(*reinterpret_cast<const float4*>(mp),
                     *reinterpret_cast<const float4*>(mp + 4));
    }

    const f32x4 ZV = {0.f, 0.f, 0.f, 0.f};
    f32x4 acc[2][4];                     // [t-tile local][o-tile 0..3] — static idx only
    #pragma unroll
    for (int t = 0; t < 2; ++t)
        #pragma unroll
        for (int o = 0; o < 4; ++o) acc[t][o] = ZV;

    __syncthreads();                     // x staged, bias ready

    #pragma unroll 1
    for (int cchunk = 0; cchunk < 2; ++cchunk) {
        const int c0 = cchunk * 32;
        #pragma unroll
        for (int oh = 0; oh < 2; ++oh) {   // compile-time: acc index static

            // ---- hyper: 12 tiles/wave = 2 groups of 6 ----
            #pragma unroll 1
            for (int ou = 0; ou < 2; ++ou) {
                const int o_l = wave * 2 + ou;       // 0..31 within half
                const int og  = oh * 32 + o_l;       // global o
                #pragma unroll
                for (int ch = 0; ch < 2; ++ch) {
                    #pragma unroll
                    for (int k = 0; k < 3; ++k) {
                        const int pr = og * 192 + (c0 + ch * 16 + l16) * 3 + k;
                        bf16x8 aF;
                        f32x4 Cf;
                        if constexpr (USE_WS) {
                            aF = *reinterpret_cast<const bf16x8*>(wlwbf + (size_t)pr * M_DIM + g * 8);
                            const float4 cf = *reinterpret_cast<const float4*>(
                                wlbR + (og * 3 + k) * 64 + c0 + ch * 16 + g * 4);
                            Cf[0] = cf.x; Cf[1] = cf.y; Cf[2] = cf.z; Cf[3] = cf.w;
                        } else {
                            const float* wp = wlw + (size_t)pr * M_DIM + g * 8;
                            aF = cvt8(*reinterpret_cast<const float4*>(wp),
                                      *reinterpret_cast<const float4*>(wp + 4));
                            const int cb = c0 + ch * 16 + g * 4;
                            const int pb = og * 192 + k;
                            Cf[0] = wlb[pb + (cb + 0) * 3];
                            Cf[1] = wlb[pb + (cb + 1) * 3];
                            Cf[2] = wlb[pb + (cb + 2) * 3];
                            Cf[3] = wlb[pb + (cb + 3) * 3];
                        }
                        const f32x4 d = __builtin_amdgcn_mfma_f32_16x16x32_bf16(aF, metaF, Cf, 0, 0, 0);
                        if (l16 < NT) {
                            const int off = l16 * NODESTR + o_l * OSTR + k * 32 + ch * 16 + g * 4;
                            *reinterpret_cast<short4*>(&wsh[off]) =
                                make_short4(f2bf(d[0]), f2bf(d[1]), f2bf(d[2]), f2bf(d[3]));
                        }
                    }
                }
            }
            __syncthreads();             // w ready for conv

            // ---- conv: B-frags (LDS), A-frags (swizzled LDS), 12 MFMA ----
            const short* wn = wsh + node * NODESTR;
            const short* xn = xsh + node * 4096;
            bf16x8 B[2][3];
            #pragma unroll
            for (int ol = 0; ol < 2; ++ol)
                #pragma unroll
                for (int k = 0; k < 3; ++k)
                    B[ol][k] = *reinterpret_cast<const bf16x8*>(
                        wn + (ol * 16 + l16) * OSTR + k * 32 + g * 8);

            #pragma unroll
            for (int ttl = 0; ttl < 2; ++ttl) {
                #pragma unroll
                for (int k = 0; k < 3; ++k) {
                    int row = thalf * 32 + ttl * 16 + l16 + k;
                    row = row < 63 ? row : 63;         // rows t>=62 discarded
                    const int so = (c0 + g * 8) ^ ((row & 7) << 3);
                    const bf16x8 A = *reinterpret_cast<const bf16x8*>(
                        xn + row * 64 + so);
                    #pragma unroll
                    for (int ol = 0; ol < 2; ++ol)
                        acc[ttl][oh * 2 + ol] = __builtin_amdgcn_mfma_f32_16x16x32_bf16(
                            A, B[ol][k], acc[ttl][oh * 2 + ol], 0, 0, 0);
                }
            }
            __syncthreads();             // conv done before next hyper overwrite
        }
    }

    // ---------------- epilogue: add bias, store f32 ----------------
    float* ob = out + (size_t)(bn0 + node) * (S_OUT * C_OUT);
    #pragma unroll
    for (int ttl = 0; ttl < 2; ++ttl) {
        #pragma unroll
        for (int ot = 0; ot < 4; ++ot) {
            const int o  = ot * 16 + l16;
            const float bv = bias_s[node][o];
            #pragma unroll
            for (int r = 0; r < 4; ++r) {
                const int t = thalf * 32 + ttl * 16 + g * 4 + r;
                if (t < S_OUT) ob[t * C_OUT + o] = acc[ttl][ot][r] + bv;
            }
        }
    }
}

extern "C" void kernel_launch(void* const* d_in, const int* in_sizes, int n_in,
                              void* d_out, int out_size, void* d_ws, size_t ws_size,
                              hipStream_t stream) {
    const float* meta = (const float*)d_in[0];
    const float* x    = (const float*)d_in[1];
    const float* wlw  = (const float*)d_in[2];
    const float* wlb  = (const float*)d_in[3];
    const float* blw  = (const float*)d_in[4];
    const float* blb  = (const float*)d_in[5];
    float* out = (float*)d_out;
    (void)in_sizes; (void)n_in; (void)out_size;

    short* wlwbf = (short*)d_ws;
    float* wlbR  = (float*)((char*)d_ws + (size_t)WLW_ROWS * M_DIM * 2);

    if (ws_size >= (size_t)WS_NEED) {
        (void)hipFuncSetAttribute((const void*)&metaconv_fused<1>,
                                  hipFuncAttributeMaxDynamicSharedMemorySize, DYNB);
        wlw_to_bf16<<<dim3(WLW_ROWS * M_DIM / (256 * 8)), dim3(256), 0, stream>>>(wlw, wlwbf);
        wlb_rearr<<<dim3(WLW_ROWS / 256), dim3(256), 0, stream>>>(wlb, wlbR);
        metaconv_fused<1><<<dim3(BN_TOT / NT), dim3(NTHREADS), DYNB, stream>>>(
            meta, x, wlw, wlwbf, wlb, wlbR, blw, blb, out);
    } else {
        (void)hipFuncSetAttribute((const void*)&metaconv_fused<0>,
                                  hipFuncAttributeMaxDynamicSharedMemorySize, DYNB);
        metaconv_fused<0><<<dim3(BN_TOT / NT), dim3(NTHREADS), DYNB, stream>>>(
            meta, x, wlw, wlwbf, wlb, wlbR, blw, blb, out);
    }
}

// Round 7
// 142.927 us; speedup vs baseline: 1.6120x; 1.0016x over previous
//
#include <hip/hip_runtime.h>
#include <hip/hip_bf16.h>

// MetaConv2d fused hypernetwork + dynamic conv, bf16 MFMA. Round 7.
// out[bn,t,o] = sum_{c,k} x[bn,t+k,c] * w[bn,o,c,k] + bias[bn,o]
//   w[bn,p]   = meta[bn,:]·w_lin_w[p,:] + w_lin_b[p],  p = o*192 + c*3 + k
//
// Block = 8 nodes, 1024 threads (16 waves = 8 nodes x 2 t-halves), grid 1024.
// Software-pipelined 8-phase schedule (2 c-chunks x 4 o-quarters):
//   phase P: [P==0: issue x-chunk1 global loads (regs, T14)]
//            hyper(P+1) -> wbuf[(P+1)&1]   (6 tiles/wave: 1 o-row x 2 ch x 3 k)
//            conv(P)    <- wbuf[P&1], xbuf[cc]  (3 B + 6 A ds_reads, 6 MFMA)
//            [P==3: ds_write x-chunk1 -> xbuf1]
//            s_waitcnt lgkmcnt(0); s_barrier   (vmcnt NOT drained -> loads
//                                               stay in flight across phases)
// LDS: dynamic 135.4 KB = x 2x40 KB (stride-40 rows: 2-way banks, no swizzle)
//      + w 2x26.8 KB (WNODE=1672: hyper-writes/B-reads <=2-way); static 2 KB bias.
// All acc indices compile-time (rule #20); raw barrier keeps vmcnt outstanding.

#define BN_TOT   8192
#define C_IN     64
#define C_OUT    64
#define M_DIM    32
#define S_OUT    62

#define NT       8            // nodes per block
#define NTHREADS 1024         // 16 waves
#define XSTR     40           // shorts per x row (32 c + 8 pad) -> 2-way banks
#define XNODE    (64 * XSTR)  // 2560 shorts per node per chunk
#define XBUF     (NT * XNODE) // 20480 shorts per chunk buffer
#define OSTR     104          // shorts per o-row in w (96 j + 8 pad)
#define WNODE    (16 * OSTR + 8)   // 1672 shorts (dw%32==4 -> writes spread)
#define WBUF     (NT * WNODE)      // 13376 shorts per w buffer
#define DYNSH    (2 * XBUF + 2 * WBUF)   // 67712 shorts
#define DYNB     (DYNSH * 2)             // 135424 B
#define WLW_ROWS 12288
#define WS_NEED  (WLW_ROWS * M_DIM * 2 + WLW_ROWS * 4)

typedef __attribute__((ext_vector_type(8))) short bf16x8;
typedef __attribute__((ext_vector_type(4))) float f32x4;

static __device__ __forceinline__ short f2bf(float f) {
    return __bfloat16_as_short(__float2bfloat16(f));
}

static __device__ __forceinline__ bf16x8 cvt8(float4 a, float4 b) {
    bf16x8 r;
    r[0] = f2bf(a.x); r[1] = f2bf(a.y); r[2] = f2bf(a.z); r[3] = f2bf(a.w);
    r[4] = f2bf(b.x); r[5] = f2bf(b.y); r[6] = f2bf(b.z); r[7] = f2bf(b.w);
    return r;
}

// barrier with LDS visibility only: do NOT drain vmcnt (keeps the T14
// x-chunk global loads in flight across phase boundaries).
static __device__ __forceinline__ void barrier_lgkm() {
    asm volatile("s_waitcnt lgkmcnt(0)" ::: "memory");
    __builtin_amdgcn_s_barrier();
    asm volatile("" ::: "memory");
}

// ---------------- pre-pass 1: w_lin_w f32 -> bf16 ----------------
extern "C" __global__ void wlw_to_bf16(const float* __restrict__ src,
                                       short* __restrict__ dst) {
    const int i = (blockIdx.x * 256 + threadIdx.x) * 8;
    const float4 a = *reinterpret_cast<const float4*>(src + i);
    const float4 b = *reinterpret_cast<const float4*>(src + i + 4);
    *reinterpret_cast<bf16x8*>(dst + i) = cvt8(a, b);
}

// ---------------- pre-pass 2: wlb -> wlbR[o][k][c] f32 ----------------
extern "C" __global__ void wlb_rearr(const float* __restrict__ wlb,
                                     float* __restrict__ wlbR) {
    const int i = blockIdx.x * 256 + threadIdx.x;
    const int o = i / 192;
    const int r = i - o * 192;
    const int k = r >> 6;
    const int c = r & 63;
    wlbR[i] = wlb[o * 192 + c * 3 + k];
}

struct XReg { float4 a0, a1, b0, b1; };   // one x chunk's loads per thread

// ---------------- fused kernel ----------------
template <int USE_WS>
__global__ void __launch_bounds__(NTHREADS, 4)
metaconv_fused(const float* __restrict__ meta,   // [8192][32]
               const float* __restrict__ x,      // [8192][64][64]
               const float* __restrict__ wlw,    // [12288][32] f32
               const short* __restrict__ wlwbf,  // [12288][32] bf16 (ws)
               const float* __restrict__ wlb,    // [12288]
               const float* __restrict__ wlbR,   // [64][3][64] (ws)
               const float* __restrict__ blw,    // [64][32]
               const float* __restrict__ blb,    // [64]
               float* __restrict__ out)          // [8192][62][64]
{
    extern __shared__ __align__(16) short dynsm[];
    short* xbuf = dynsm;                  // [2][NT][64][XSTR]
    short* wbuf = dynsm + 2 * XBUF;       // [2][NT][WNODE]
    __shared__ float bias_s[NT][C_OUT];

    const int tid   = threadIdx.x;
    const int wave  = tid >> 6;           // 0..15
    const int lane  = tid & 63;
    const int l16   = lane & 15;
    const int g     = lane >> 4;
    const int node  = wave & (NT - 1);
    const int thalf = wave >> 3;
    const int bn0   = blockIdx.x * NT;

    const float* xsrc = x + (size_t)(bn0 + node) * (64 * C_IN);
    const int ts0 = thalf * 32;
    // granule mapping: per thread 2 granules gid = i*64+lane (i=0,1):
    //   row = ts0 + (gid>>2), gr = gid&3  -> covers 32 rows x 4 granules / wave
    const int row0 = ts0 + (lane >> 2), gr0 = lane & 3;
    const int row1 = ts0 + ((64 + lane) >> 2), gr1 = lane & 3;

    auto stage_load = [&](int c0, XReg& xr) {
        const float* p0 = xsrc + row0 * 64 + c0 + gr0 * 8;
        const float* p1 = xsrc + row1 * 64 + c0 + gr1 * 8;
        xr.a0 = *reinterpret_cast<const float4*>(p0);
        xr.a1 = *reinterpret_cast<const float4*>(p0 + 4);
        xr.b0 = *reinterpret_cast<const float4*>(p1);
        xr.b1 = *reinterpret_cast<const float4*>(p1 + 4);
    };
    auto stage_write = [&](int half, const XReg& xr) {
        short* xd = xbuf + half * XBUF + node * XNODE;
        *reinterpret_cast<bf16x8*>(xd + row0 * XSTR + gr0 * 8) = cvt8(xr.a0, xr.a1);
        *reinterpret_cast<bf16x8*>(xd + row1 * XSTR + gr1 * 8) = cvt8(xr.b0, xr.b1);
    };

    // ---- prologue: issue chunk-0 loads first (HBM latency cover) ----
    XReg xr0;
    stage_load(0, xr0);

    // per-block bias table (tid < 512)
    if (tid < NT * C_OUT) {
        const int bnode = tid >> 6;
        const int o     = tid & 63;
        const float* mrow = meta + (size_t)(bn0 + bnode) * M_DIM;
        const float* brow = blw + o * M_DIM;
        float s = blb[o];
        #pragma unroll
        for (int m = 0; m < M_DIM; ++m) s += mrow[m] * brow[m];
        bias_s[bnode][o] = s;
    }

    // meta B-fragment (cols = nodes; cols 8..15 duplicate, discarded on write)
    bf16x8 metaF;
    {
        const float* mp = meta + (size_t)(bn0 + (l16 & (NT - 1))) * M_DIM + g * 8;
        metaF = cvt8(*reinterpret_cast<const float4*>(mp),
                     *reinterpret_cast<const float4*>(mp + 4));
    }

    // hyper: one o-row per wave (og = oq*16 + wave), 2 ch x 3 k = 6 tiles.
    // D lane(l16,g): col=node=l16 (valid l16<NT), rows cc_local = ch*16+g*4+r.
    auto hyper = [&](int oq, int c0, int half) {
        const int og = oq * 16 + wave;
        short* wd = wbuf + half * WBUF;
        #pragma unroll
        for (int ch = 0; ch < 2; ++ch) {
            #pragma unroll
            for (int k = 0; k < 3; ++k) {
                const int pr = og * 192 + (c0 + ch * 16 + l16) * 3 + k;
                bf16x8 aF;
                f32x4 Cf;
                if constexpr (USE_WS) {
                    aF = *reinterpret_cast<const bf16x8*>(wlwbf + (size_t)pr * M_DIM + g * 8);
                    const float4 cf = *reinterpret_cast<const float4*>(
                        wlbR + (og * 3 + k) * 64 + c0 + ch * 16 + g * 4);
                    Cf[0] = cf.x; Cf[1] = cf.y; Cf[2] = cf.z; Cf[3] = cf.w;
                } else {
                    const float* wp = wlw + (size_t)pr * M_DIM + g * 8;
                    aF = cvt8(*reinterpret_cast<const float4*>(wp),
                              *reinterpret_cast<const float4*>(wp + 4));
                    const int cb = c0 + ch * 16 + g * 4;
                    const int pb = og * 192 + k;
                    Cf[0] = wlb[pb + (cb + 0) * 3];
                    Cf[1] = wlb[pb + (cb + 1) * 3];
                    Cf[2] = wlb[pb + (cb + 2) * 3];
                    Cf[3] = wlb[pb + (cb + 3) * 3];
                }
                const f32x4 d = __builtin_amdgcn_mfma_f32_16x16x32_bf16(aF, metaF, Cf, 0, 0, 0);
                if (l16 < NT) {
                    const int off = l16 * WNODE + wave * OSTR + k * 32 + ch * 16 + g * 4;
                    *reinterpret_cast<short4*>(&wd[off]) =
                        make_short4(f2bf(d[0]), f2bf(d[1]), f2bf(d[2]), f2bf(d[3]));
                }
            }
        }
    };

    const f32x4 ZV = {0.f, 0.f, 0.f, 0.f};
    f32x4 acc[2][4];                      // [t-tile local][o-quarter] — static idx
    #pragma unroll
    for (int t = 0; t < 2; ++t)
        #pragma unroll
        for (int o = 0; o < 4; ++o) acc[t][o] = ZV;

    // conv: one o-quarter per phase; 3 B-frags + 6 A-frags, 6 MFMA.
    auto conv = [&](int oq, int cc, int half) {
        const short* wn = wbuf + half * WBUF + node * WNODE;
        const short* xn = xbuf + cc * XBUF + node * XNODE;
        bf16x8 B[3];
        #pragma unroll
        for (int k = 0; k < 3; ++k)
            B[k] = *reinterpret_cast<const bf16x8*>(wn + l16 * OSTR + k * 32 + g * 8);
        #pragma unroll
        for (int ttl = 0; ttl < 2; ++ttl) {
            #pragma unroll
            for (int k = 0; k < 3; ++k) {
                int row = thalf * 32 + ttl * 16 + l16 + k;
                row = row < 63 ? row : 63;          // rows t>=62 discarded
                const bf16x8 A = *reinterpret_cast<const bf16x8*>(
                    xn + row * XSTR + g * 8);
                acc[ttl][oq] = __builtin_amdgcn_mfma_f32_16x16x32_bf16(
                    A, B[k], acc[ttl][oq], 0, 0, 0);
            }
        }
    };

    // prologue compute: write chunk 0, hyper phase 0 -> wbuf0
    stage_write(0, xr0);
    hyper(0, 0, 0);
    barrier_lgkm();

    // ---- main 8-phase pipeline ----
    XReg xr1;
    #pragma unroll
    for (int cc = 0; cc < 2; ++cc) {
        #pragma unroll
        for (int oq = 0; oq < 4; ++oq) {
            const int P = cc * 4 + oq;
            if (P == 0) stage_load(32, xr1);         // chunk-1 loads in flight P0..P3
            if (P < 7) {
                const int Pn = P + 1;
                hyper(Pn & 3, (Pn >> 2) * 32, Pn & 1);
            }
            conv(oq, cc, P & 1);
            if (P == 3) stage_write(1, xr1);         // vmcnt wait emitted here by use
            barrier_lgkm();
        }
    }

    // ---------------- epilogue: add bias, store f32 ----------------
    float* ob = out + (size_t)(bn0 + node) * (S_OUT * C_OUT);
    #pragma unroll
    for (int ttl = 0; ttl < 2; ++ttl) {
        #pragma unroll
        for (int ot = 0; ot < 4; ++ot) {
            const int o  = ot * 16 + l16;
            const float bv = bias_s[node][o];
            #pragma unroll
            for (int r = 0; r < 4; ++r) {
                const int t = thalf * 32 + ttl * 16 + g * 4 + r;
                if (t < S_OUT) ob[t * C_OUT + o] = acc[ttl][ot][r] + bv;
            }
        }
    }
}

extern "C" void kernel_launch(void* const* d_in, const int* in_sizes, int n_in,
                              void* d_out, int out_size, void* d_ws, size_t ws_size,
                              hipStream_t stream) {
    const float* meta = (const float*)d_in[0];
    const float* x    = (const float*)d_in[1];
    const float* wlw  = (const float*)d_in[2];
    const float* wlb  = (const float*)d_in[3];
    const float* blw  = (const float*)d_in[4];
    const float* blb  = (const float*)d_in[5];
    float* out = (float*)d_out;
    (void)in_sizes; (void)n_in; (void)out_size;

    short* wlwbf = (short*)d_ws;
    float* wlbR  = (float*)((char*)d_ws + (size_t)WLW_ROWS * M_DIM * 2);

    if (ws_size >= (size_t)WS_NEED) {
        (void)hipFuncSetAttribute((const void*)&metaconv_fused<1>,
                                  hipFuncAttributeMaxDynamicSharedMemorySize, DYNB);
        wlw_to_bf16<<<dim3(WLW_ROWS * M_DIM / (256 * 8)), dim3(256), 0, stream>>>(wlw, wlwbf);
        wlb_rearr<<<dim3(WLW_ROWS / 256), dim3(256), 0, stream>>>(wlb, wlbR);
        metaconv_fused<1><<<dim3(BN_TOT / NT), dim3(NTHREADS), DYNB, stream>>>(
            meta, x, wlw, wlwbf, wlb, wlbR, blw, blb, out);
    } else {
        (void)hipFuncSetAttribute((const void*)&metaconv_fused<0>,
                                  hipFuncAttributeMaxDynamicSharedMemorySize, DYNB);
        metaconv_fused<0><<<dim3(BN_TOT / NT), dim3(NTHREADS), DYNB, stream>>>(
            meta, x, wlw, wlwbf, wlb, wlbR, blw, blb, out);
    }
}